// Round 12
// baseline (48.476 us; speedup 1.0000x reference)
//
#include <hip/hip_runtime.h>

// LocalLinear: out[b,j] = sum_{e: rows[e]==j} x[b, cols[e]] * w[e] + bias[j]
// B=32, N_IN=65536, N_OUT=65536, NNZ=2097152 (rows sorted, int32).
// R12: batch-split two-pass. Each pass gathers a 2 MB half-table (16 bf16
// per column) -> L2-resident per XCD (R9: 4 MB table = 100% gather miss).
// R8 skeleton: 512 thr, 4-lane groups, lane-distributed cols/wgt + shfl,
// half-split edge ranges. No nt hints (R11: -25%), no min-wave cap (R9: spill).

typedef unsigned int u32;

static __device__ __forceinline__ u32 f2bf_bits(float f) {   // RNE f32->bf16
  u32 b = __builtin_bit_cast(u32, f);
  return (b + 0x7fffu + ((b >> 16) & 1u)) >> 16;
}
static __device__ __forceinline__ float bf_lo(u32 u) {
  return __builtin_bit_cast(float, u << 16);
}
static __device__ __forceinline__ float bf_hi(u32 u) {
  return __builtin_bit_cast(float, u & 0xffff0000u);
}

// ---------------- Prep: transpose x -> two 2MB bf16 half-tables + row_ptr ----------------
// Half-table p holds batches [16p, 16p+16): xTb[p][c*8 + bp] = bf16 pair
// (batch 16p+2bp, 16p+2bp+1) of column c.
__global__ __launch_bounds__(256) void prep_kernel(
    const float* __restrict__ x, u32* __restrict__ xTb0, u32* __restrict__ xTb1,
    const int* __restrict__ rows, int* __restrict__ row_ptr,
    int n_in, int n_out, int nnz, int tblocks) {
  if ((int)blockIdx.x < tblocks) {
    __shared__ float t[32][65];
    int c0 = blockIdx.x * 64;
    if (c0 + 64 <= n_in) {
      const float4* x4 = (const float4*)x;
      for (int idx = threadIdx.x; idx < 32 * 16; idx += 256) {
        int b = idx >> 4, q = idx & 15;
        float4 v = x4[((size_t)b * n_in + c0) / 4 + q];
        t[b][q * 4 + 0] = v.x; t[b][q * 4 + 1] = v.y;
        t[b][q * 4 + 2] = v.z; t[b][q * 4 + 3] = v.w;
      }
    } else {
      for (int idx = threadIdx.x; idx < 32 * 64; idx += 256) {
        int b = idx >> 6, cl = idx & 63;
        int c = c0 + cl;
        t[b][cl] = (c < n_in) ? x[(size_t)b * n_in + c] : 0.f;
      }
    }
    __syncthreads();
    for (int idx = threadIdx.x; idx < 64 * 16; idx += 256) {
      int cl = idx >> 4, bp = idx & 15;   // bp = batch pair 0..15
      int c = c0 + cl;
      if (c < n_in) {
        u32 v = f2bf_bits(t[2 * bp][cl]) | (f2bf_bits(t[2 * bp + 1][cl]) << 16);
        u32* dst = (bp < 8) ? xTb0 : xTb1;
        dst[(size_t)c * 8 + (bp & 7)] = v;
      }
    }
  } else {
    // scatter CSR build: row_ptr[j] = first e with rows[e] >= j
    int e = ((int)blockIdx.x - tblocks) * 256 + threadIdx.x;
    if (e < nnz) {
      int r = rows[e];
      int rp = (e == 0) ? -1 : rows[e - 1];
      for (int j = rp + 1; j <= r; ++j) row_ptr[j] = e;
      if (e == nnz - 1)
        for (int j = r + 1; j <= n_out; ++j) row_ptr[j] = nnz;
    }
  }
}

// ---------------- Main pass: 16 batches, 4-lane groups, half-split, shfl ----------------
// 512 threads = 8 waves. Waves 0-3: half 0, waves 4-7: half 1 of the same 64 j's.
// Half h processes edge chunks [s+4h + 8k, +4). Lane l gathers uint2 =
// batches-in-pass 4l..4l+3 of the 32 B column.
__global__ __launch_bounds__(512) void ll_pass_kernel(
    const uint2* __restrict__ xTp2,     // n_in x 4 uint2 (column = 32 B)
    const float* __restrict__ wgt,
    const float4* __restrict__ bias4,
    const int* __restrict__ cols,
    const int* __restrict__ row_ptr,
    float4* __restrict__ out4, int n_out, int pass) {
  __shared__ float tile[16][65];
  int tid = threadIdx.x;
  int lane = tid & 63;
  int l = lane & 3;              // lane in group: pass-batches 4l..4l+3
  int gw = lane >> 2;            // group within wave 0..15
  int wv = tid >> 6;             // wave 0..7
  int half = wv >> 2;            // 0 or 1
  int g = (wv & 3) * 16 + gw;    // group 0..63 == local j
  int gb = lane & 60;            // group base lane (for shfl)
  int jb = blockIdx.x * 64;
  int j = jb + g;
  float a0 = 0, a1 = 0, a2 = 0, a3 = 0;
  if (j < n_out) {
    int s = row_ptr[j], e = row_ptr[j + 1];
    int last = e - 1;
    for (int base = s + half * 4; base < e; base += 8) {
      int il = min(base + l, last);
      int cl_ = cols[il];                                  // 4 edges per instr
      float wl_ = (base + l <= last) ? wgt[il] : 0.f;
#define EDGE_K(K) { \
      int   ck = __shfl(cl_, gb | K); \
      float wk = __shfl(wl_, gb | K); \
      uint2 v  = xTp2[(size_t)ck * 4 + l]; \
      a0 = fmaf(wk, bf_lo(v.x), a0); a1 = fmaf(wk, bf_hi(v.x), a1); \
      a2 = fmaf(wk, bf_lo(v.y), a2); a3 = fmaf(wk, bf_hi(v.y), a3); }
      EDGE_K(0) EDGE_K(1) EDGE_K(2) EDGE_K(3)
#undef EDGE_K
    }
  }
  int b0 = l * 4;
  if (half == 0) {
    tile[b0 + 0][g] = a0; tile[b0 + 1][g] = a1;
    tile[b0 + 2][g] = a2; tile[b0 + 3][g] = a3;
  }
  __syncthreads();
  if (half == 1) {
    tile[b0 + 0][g] += a0; tile[b0 + 1][g] += a1;
    tile[b0 + 2][g] += a2; tile[b0 + 3][g] += a3;
  }
  __syncthreads();
  // writeout: 16 pass-rows x 64 j's = 16x16 float4 (+bias), threads 0..255
  if (tid < 256) {
    int bb = tid >> 4, q = tid & 15;
    int jj = jb + q * 4;
    int brow = pass * 16 + bb;
    if (jj + 3 < n_out) {
      float4 bv = bias4[jj / 4];
      float4 o;
      o.x = tile[bb][q * 4 + 0] + bv.x;
      o.y = tile[bb][q * 4 + 1] + bv.y;
      o.z = tile[bb][q * 4 + 2] + bv.z;
      o.w = tile[bb][q * 4 + 3] + bv.w;
      out4[((size_t)brow * n_out + jj) / 4] = o;
    } else {
      float* out = (float*)out4;
      const float* bias = (const float*)bias4;
      for (int d = 0; d < 4; ++d)
        if (jj + d < n_out)
          out[(size_t)brow * n_out + jj + d] = tile[bb][q * 4 + d] + bias[jj + d];
    }
  }
}

// ---------------- Fallback: fp32 path (R4, known-good) ----------------
__global__ __launch_bounds__(256) void transpose_x_kernel(
    const float* __restrict__ x, float* __restrict__ xT, int n_in) {
  __shared__ float t[32][65];
  int c0 = blockIdx.x * 64;
  for (int idx = threadIdx.x; idx < 32 * 64; idx += 256) {
    int b = idx >> 6, cl = idx & 63;
    int c = c0 + cl;
    t[b][cl] = (c < n_in) ? x[(size_t)b * n_in + c] : 0.0f;
  }
  __syncthreads();
  for (int idx = threadIdx.x; idx < 64 * 32; idx += 256) {
    int cl = idx >> 5, b = idx & 31;
    int c = c0 + cl;
    if (c < n_in) xT[(size_t)c * 32 + b] = t[b][cl];
  }
}

__global__ __launch_bounds__(256) void build_rowptr_bs_kernel(
    const int* __restrict__ rows, int* __restrict__ row_ptr, int nnz, int n_out) {
  int j = blockIdx.x * blockDim.x + threadIdx.x;
  if (j > n_out) return;
  int lo = 0, hi = nnz;
  while (lo < hi) { int m = (lo + hi) >> 1; if (rows[m] < j) lo = m + 1; else hi = m; }
  row_ptr[j] = lo;
}

__global__ __launch_bounds__(256) void ll_main4_kernel(
    const float4* __restrict__ xT4,
    const float* __restrict__ wgt,
    const float* __restrict__ bias,
    const int* __restrict__ cols,
    const int* __restrict__ row_ptr,
    float* __restrict__ out, int n_out) {
  __shared__ float tile[32][33];
  int tid = threadIdx.x;
  int g = tid >> 3;
  int l = tid & 7;
  int jb = blockIdx.x * 32;
  int j = jb + g;
  float ax = 0.f, ay = 0.f, az = 0.f, aw = 0.f;
  if (j < n_out) {
    int s = row_ptr[j];
    int e = row_ptr[j + 1];
    for (int base = s; base < e; base += 4) {
      int last = e - 1;
      int i1 = min(base + 1, last), i2 = min(base + 2, last), i3 = min(base + 3, last);
      int c0 = cols[base], c1 = cols[i1], c2 = cols[i2], c3 = cols[i3];
      float w0 = wgt[base];
      float w1 = (base + 1 <= last) ? wgt[i1] : 0.f;
      float w2 = (base + 2 <= last) ? wgt[i2] : 0.f;
      float w3 = (base + 3 <= last) ? wgt[i3] : 0.f;
      float4 x0 = xT4[(size_t)c0 * 8 + l];
      float4 x1 = xT4[(size_t)c1 * 8 + l];
      float4 x2 = xT4[(size_t)c2 * 8 + l];
      float4 x3 = xT4[(size_t)c3 * 8 + l];
      ax = fmaf(w0, x0.x, ax); ay = fmaf(w0, x0.y, ay);
      az = fmaf(w0, x0.z, az); aw = fmaf(w0, x0.w, aw);
      ax = fmaf(w1, x1.x, ax); ay = fmaf(w1, x1.y, ay);
      az = fmaf(w1, x1.z, az); aw = fmaf(w1, x1.w, aw);
      ax = fmaf(w2, x2.x, ax); ay = fmaf(w2, x2.y, ay);
      az = fmaf(w2, x2.z, az); aw = fmaf(w2, x2.w, aw);
      ax = fmaf(w3, x3.x, ax); ay = fmaf(w3, x3.y, ay);
      az = fmaf(w3, x3.z, az); aw = fmaf(w3, x3.w, aw);
    }
  }
  tile[l * 4 + 0][g] = ax;
  tile[l * 4 + 1][g] = ay;
  tile[l * 4 + 2][g] = az;
  tile[l * 4 + 3][g] = aw;
  __syncthreads();
  for (int idx = tid; idx < 32 * 32; idx += 256) {
    int bb = idx >> 5, jl = idx & 31;
    int jj = jb + jl;
    if (jj < n_out) out[(size_t)bb * n_out + jj] = tile[bb][jl] + bias[jj];
  }
}

__global__ __launch_bounds__(256) void ll_naive_kernel(
    const float* __restrict__ x,
    const float* __restrict__ wgt,
    const float* __restrict__ bias,
    const int* __restrict__ rows,
    const int* __restrict__ cols,
    float* __restrict__ out,
    int n_in, int n_out, int nnz, int B) {
  int idx = blockIdx.x * blockDim.x + threadIdx.x;
  if (idx >= n_out * B) return;
  int j = idx % n_out;
  int b = idx / n_out;
  int lo = 0, hi = nnz;
  while (lo < hi) { int m = (lo + hi) >> 1; if (rows[m] < j) lo = m + 1; else hi = m; }
  int s = lo;
  hi = nnz;
  while (lo < hi) { int m = (lo + hi) >> 1; if (rows[m] <= j) lo = m + 1; else hi = m; }
  int e = lo;
  float acc = 0.0f;
  for (int t = s; t < e; ++t)
    acc = fmaf(wgt[t], x[(size_t)b * n_in + cols[t]], acc);
  out[(size_t)b * n_out + j] = acc + bias[j];
}

extern "C" void kernel_launch(void* const* d_in, const int* in_sizes, int n_in_arrays,
                              void* d_out, int out_size, void* d_ws, size_t ws_size,
                              hipStream_t stream) {
  const float* x    = (const float*)d_in[0];
  const float* wgt  = (const float*)d_in[1];
  const float* bias = (const float*)d_in[2];
  const int*   rows = (const int*)d_in[3];
  const int*   cols = (const int*)d_in[4];
  float* out = (float*)d_out;

  const int nnz   = in_sizes[1];
  const int n_out = in_sizes[2];
  const int B     = out_size / n_out;           // 32
  const int n_in  = in_sizes[0] / B;            // 65536

  const size_t half_bytes = (size_t)n_in * 8 * sizeof(u32);    // 2 MB half-table
  const size_t xT_bytes   = (size_t)n_in * 32 * sizeof(float); // fp32 table
  const size_t rp_bytes   = (size_t)(n_out + 1) * sizeof(int);

  if (B == 32 && ws_size >= 2 * half_bytes + rp_bytes) {
    u32* xTb0 = (u32*)d_ws;
    u32* xTb1 = (u32*)((char*)d_ws + half_bytes);
    int* row_ptr = (int*)((char*)d_ws + 2 * half_bytes);
    int tblocks = (n_in + 63) / 64;
    int eblocks = (nnz + 255) / 256;
    prep_kernel<<<tblocks + eblocks, 256, 0, stream>>>(
        x, xTb0, xTb1, rows, row_ptr, n_in, n_out, nnz, tblocks);
    int jblocks = (n_out + 63) / 64;
    ll_pass_kernel<<<jblocks, 512, 0, stream>>>(
        (const uint2*)xTb0, wgt, (const float4*)bias, cols, row_ptr,
        (float4*)out, n_out, 0);
    ll_pass_kernel<<<jblocks, 512, 0, stream>>>(
        (const uint2*)xTb1, wgt, (const float4*)bias, cols, row_ptr,
        (float4*)out, n_out, 1);
  } else if (B == 32 && ws_size >= xT_bytes + rp_bytes) {
    float* xT = (float*)d_ws;
    int* row_ptr = (int*)((char*)d_ws + xT_bytes);
    transpose_x_kernel<<<(n_in + 63) / 64, 256, 0, stream>>>(x, xT, n_in);
    build_rowptr_bs_kernel<<<(n_out + 256) / 256, 256, 0, stream>>>(rows, row_ptr, nnz, n_out);
    ll_main4_kernel<<<(n_out + 31) / 32, 256, 0, stream>>>(
        (const float4*)xT, wgt, bias, cols, row_ptr, out, n_out);
  } else {
    int total = n_out * B;
    ll_naive_kernel<<<(total + 255) / 256, 256, 0, stream>>>(
        x, wgt, bias, rows, cols, out, n_in, n_out, nnz, B);
  }
}

// Round 13
// 37.855 us; speedup vs baseline: 1.2806x; 1.2806x over previous
//
#include <hip/hip_runtime.h>

// LocalLinear: out[b,j] = sum_{e: rows[e]==j} x[b, cols[e]] * w[e] + bias[j]
// B=32, N_IN=65536, N_OUT=65536, NNZ=2097152 (rows sorted, int32).
// R13 = exact revert to R8 (best measured: 37.8 us).
// 512-thread blocks (32 waves/CU), lane-distributed cols/wgt loads +
// shfl broadcast, scatter-built row_ptr, bf16 xT table (4 MB).
// Tried and rejected: LDS edge staging (R9: VGPR spill via launch-bounds cap),
// nt hints (R11: -25%, kills metadata L1 reuse), batch-split 2-pass (R12: -28%,
// L2 residency never materializes under stream pressure).

typedef unsigned int u32;

static __device__ __forceinline__ u32 f2bf_bits(float f) {   // RNE f32->bf16
  u32 b = __builtin_bit_cast(u32, f);
  return (b + 0x7fffu + ((b >> 16) & 1u)) >> 16;
}
static __device__ __forceinline__ float bf_lo(u32 u) {
  return __builtin_bit_cast(float, u << 16);
}
static __device__ __forceinline__ float bf_hi(u32 u) {
  return __builtin_bit_cast(float, u & 0xffff0000u);
}

// ---------------- Prep: transpose x -> bf16 xT  +  scatter row_ptr (fused) ----------------
__global__ __launch_bounds__(256) void prep_kernel(
    const float* __restrict__ x, u32* __restrict__ xTb,   // xTb: n_in x 16 u32 (32 bf16)
    const int* __restrict__ rows, int* __restrict__ row_ptr,
    int n_in, int n_out, int nnz, int tblocks) {
  if ((int)blockIdx.x < tblocks) {
    __shared__ float t[32][65];
    int c0 = blockIdx.x * 64;
    if (c0 + 64 <= n_in) {
      const float4* x4 = (const float4*)x;
      for (int idx = threadIdx.x; idx < 32 * 16; idx += 256) {
        int b = idx >> 4, q = idx & 15;
        float4 v = x4[((size_t)b * n_in + c0) / 4 + q];
        t[b][q * 4 + 0] = v.x; t[b][q * 4 + 1] = v.y;
        t[b][q * 4 + 2] = v.z; t[b][q * 4 + 3] = v.w;
      }
    } else {
      for (int idx = threadIdx.x; idx < 32 * 64; idx += 256) {
        int b = idx >> 6, cl = idx & 63;
        int c = c0 + cl;
        t[b][cl] = (c < n_in) ? x[(size_t)b * n_in + c] : 0.f;
      }
    }
    __syncthreads();
    for (int idx = threadIdx.x; idx < 64 * 16; idx += 256) {
      int cl = idx >> 4, bp = idx & 15;   // bp = batch pair
      int c = c0 + cl;
      if (c < n_in) {
        u32 v = f2bf_bits(t[2 * bp][cl]) | (f2bf_bits(t[2 * bp + 1][cl]) << 16);
        xTb[(size_t)c * 16 + bp] = v;
      }
    }
  } else {
    // scatter CSR build: row_ptr[j] = first e with rows[e] >= j
    int e = ((int)blockIdx.x - tblocks) * 256 + threadIdx.x;
    if (e < nnz) {
      int r = rows[e];
      int rp = (e == 0) ? -1 : rows[e - 1];
      for (int j = rp + 1; j <= r; ++j) row_ptr[j] = e;
      if (e == nnz - 1)
        for (int j = r + 1; j <= n_out; ++j) row_ptr[j] = nnz;
    }
  }
}

// ---------------- Main: 4-lane groups, half-split edge ranges, shfl broadcast ----------------
// 512 threads = 8 waves. Waves 0-3: half 0, waves 4-7: half 1 of the same 64 j's.
// Half h processes edge chunks [s+4h + 8k, +4) — disjoint, covers [s,e).
__global__ __launch_bounds__(512, 8) void ll_main_bf16_kernel(
    const uint4* __restrict__ xTb4,     // n_in x 4 uint4 (column = 64 B)
    const float* __restrict__ wgt,
    const float4* __restrict__ bias4,
    const int* __restrict__ cols,
    const int* __restrict__ row_ptr,
    float4* __restrict__ out4, int n_out) {
  __shared__ float tile[32][65];
  int tid = threadIdx.x;
  int lane = tid & 63;
  int l = lane & 3;              // lane in group: batches 8l..8l+7
  int gw = lane >> 2;            // group within wave 0..15
  int wv = tid >> 6;             // wave 0..7
  int half = wv >> 2;            // 0 or 1
  int g = (wv & 3) * 16 + gw;    // group 0..63 == local j
  int gb = lane & 60;            // group base lane (for shfl)
  int jb = blockIdx.x * 64;
  int j = jb + g;
  float a0 = 0, a1 = 0, a2 = 0, a3 = 0, a4 = 0, a5 = 0, a6 = 0, a7 = 0;
  if (j < n_out) {
    int s = row_ptr[j], e = row_ptr[j + 1];
    int last = e - 1;
    for (int base = s + half * 4; base < e; base += 8) {
      int il = min(base + l, last);
      int cl_ = cols[il];                                  // 4 edges per instr
      float wl_ = (base + l <= last) ? wgt[il] : 0.f;
#define EDGE_K(K) { \
      int   ck = __shfl(cl_, gb | K); \
      float wk = __shfl(wl_, gb | K); \
      uint4 v  = xTb4[(size_t)ck * 4 + l]; \
      a0 = fmaf(wk, bf_lo(v.x), a0); a1 = fmaf(wk, bf_hi(v.x), a1); \
      a2 = fmaf(wk, bf_lo(v.y), a2); a3 = fmaf(wk, bf_hi(v.y), a3); \
      a4 = fmaf(wk, bf_lo(v.z), a4); a5 = fmaf(wk, bf_hi(v.z), a5); \
      a6 = fmaf(wk, bf_lo(v.w), a6); a7 = fmaf(wk, bf_hi(v.w), a7); }
      EDGE_K(0) EDGE_K(1) EDGE_K(2) EDGE_K(3)
#undef EDGE_K
    }
  }
  int b0 = l * 8;
  if (half == 0) {
    tile[b0 + 0][g] = a0; tile[b0 + 1][g] = a1; tile[b0 + 2][g] = a2; tile[b0 + 3][g] = a3;
    tile[b0 + 4][g] = a4; tile[b0 + 5][g] = a5; tile[b0 + 6][g] = a6; tile[b0 + 7][g] = a7;
  }
  __syncthreads();
  if (half == 1) {
    tile[b0 + 0][g] += a0; tile[b0 + 1][g] += a1; tile[b0 + 2][g] += a2; tile[b0 + 3][g] += a3;
    tile[b0 + 4][g] += a4; tile[b0 + 5][g] += a5; tile[b0 + 6][g] += a6; tile[b0 + 7][g] += a7;
  }
  __syncthreads();
  // vectorized writeout: 512 threads, one float4 each (32 rows x 16 quads)
  {
    int bb = tid >> 4, q = tid & 15;
    int jj = jb + q * 4;
    if (jj + 3 < n_out) {
      float4 bv = bias4[jj / 4];
      float4 o;
      o.x = tile[bb][q * 4 + 0] + bv.x;
      o.y = tile[bb][q * 4 + 1] + bv.y;
      o.z = tile[bb][q * 4 + 2] + bv.z;
      o.w = tile[bb][q * 4 + 3] + bv.w;
      out4[((size_t)bb * n_out + jj) / 4] = o;
    } else {
      float* out = (float*)out4;
      const float* bias = (const float*)bias4;
      for (int d = 0; d < 4; ++d)
        if (jj + d < n_out)
          out[(size_t)bb * n_out + jj + d] = tile[bb][q * 4 + d] + bias[jj + d];
    }
  }
}

// ---------------- Fallback: fp32 path (R4, known-good) ----------------
__global__ __launch_bounds__(256) void transpose_x_kernel(
    const float* __restrict__ x, float* __restrict__ xT, int n_in) {
  __shared__ float t[32][65];
  int c0 = blockIdx.x * 64;
  for (int idx = threadIdx.x; idx < 32 * 64; idx += 256) {
    int b = idx >> 6, cl = idx & 63;
    int c = c0 + cl;
    t[b][cl] = (c < n_in) ? x[(size_t)b * n_in + c] : 0.0f;
  }
  __syncthreads();
  for (int idx = threadIdx.x; idx < 64 * 32; idx += 256) {
    int cl = idx >> 5, b = idx & 31;
    int c = c0 + cl;
    if (c < n_in) xT[(size_t)c * 32 + b] = t[b][cl];
  }
}

__global__ __launch_bounds__(256) void build_rowptr_bs_kernel(
    const int* __restrict__ rows, int* __restrict__ row_ptr, int nnz, int n_out) {
  int j = blockIdx.x * blockDim.x + threadIdx.x;
  if (j > n_out) return;
  int lo = 0, hi = nnz;
  while (lo < hi) { int m = (lo + hi) >> 1; if (rows[m] < j) lo = m + 1; else hi = m; }
  row_ptr[j] = lo;
}

__global__ __launch_bounds__(256) void ll_main4_kernel(
    const float4* __restrict__ xT4,
    const float* __restrict__ wgt,
    const float* __restrict__ bias,
    const int* __restrict__ cols,
    const int* __restrict__ row_ptr,
    float* __restrict__ out, int n_out) {
  __shared__ float tile[32][33];
  int tid = threadIdx.x;
  int g = tid >> 3;
  int l = tid & 7;
  int jb = blockIdx.x * 32;
  int j = jb + g;
  float ax = 0.f, ay = 0.f, az = 0.f, aw = 0.f;
  if (j < n_out) {
    int s = row_ptr[j];
    int e = row_ptr[j + 1];
    for (int base = s; base < e; base += 4) {
      int last = e - 1;
      int i1 = min(base + 1, last), i2 = min(base + 2, last), i3 = min(base + 3, last);
      int c0 = cols[base], c1 = cols[i1], c2 = cols[i2], c3 = cols[i3];
      float w0 = wgt[base];
      float w1 = (base + 1 <= last) ? wgt[i1] : 0.f;
      float w2 = (base + 2 <= last) ? wgt[i2] : 0.f;
      float w3 = (base + 3 <= last) ? wgt[i3] : 0.f;
      float4 x0 = xT4[(size_t)c0 * 8 + l];
      float4 x1 = xT4[(size_t)c1 * 8 + l];
      float4 x2 = xT4[(size_t)c2 * 8 + l];
      float4 x3 = xT4[(size_t)c3 * 8 + l];
      ax = fmaf(w0, x0.x, ax); ay = fmaf(w0, x0.y, ay);
      az = fmaf(w0, x0.z, az); aw = fmaf(w0, x0.w, aw);
      ax = fmaf(w1, x1.x, ax); ay = fmaf(w1, x1.y, ay);
      az = fmaf(w1, x1.z, az); aw = fmaf(w1, x1.w, aw);
      ax = fmaf(w2, x2.x, ax); ay = fmaf(w2, x2.y, ay);
      az = fmaf(w2, x2.z, az); aw = fmaf(w2, x2.w, aw);
      ax = fmaf(w3, x3.x, ax); ay = fmaf(w3, x3.y, ay);
      az = fmaf(w3, x3.z, az); aw = fmaf(w3, x3.w, aw);
    }
  }
  tile[l * 4 + 0][g] = ax;
  tile[l * 4 + 1][g] = ay;
  tile[l * 4 + 2][g] = az;
  tile[l * 4 + 3][g] = aw;
  __syncthreads();
  for (int idx = tid; idx < 32 * 32; idx += 256) {
    int bb = idx >> 5, jl = idx & 31;
    int jj = jb + jl;
    if (jj < n_out) out[(size_t)bb * n_out + jj] = tile[bb][jl] + bias[jj];
  }
}

__global__ __launch_bounds__(256) void ll_naive_kernel(
    const float* __restrict__ x,
    const float* __restrict__ wgt,
    const float* __restrict__ bias,
    const int* __restrict__ rows,
    const int* __restrict__ cols,
    float* __restrict__ out,
    int n_in, int n_out, int nnz, int B) {
  int idx = blockIdx.x * blockDim.x + threadIdx.x;
  if (idx >= n_out * B) return;
  int j = idx % n_out;
  int b = idx / n_out;
  int lo = 0, hi = nnz;
  while (lo < hi) { int m = (lo + hi) >> 1; if (rows[m] < j) lo = m + 1; else hi = m; }
  int s = lo;
  hi = nnz;
  while (lo < hi) { int m = (lo + hi) >> 1; if (rows[m] <= j) lo = m + 1; else hi = m; }
  int e = lo;
  float acc = 0.0f;
  for (int t = s; t < e; ++t)
    acc = fmaf(wgt[t], x[(size_t)b * n_in + cols[t]], acc);
  out[(size_t)b * n_out + j] = acc + bias[j];
}

extern "C" void kernel_launch(void* const* d_in, const int* in_sizes, int n_in_arrays,
                              void* d_out, int out_size, void* d_ws, size_t ws_size,
                              hipStream_t stream) {
  const float* x    = (const float*)d_in[0];
  const float* wgt  = (const float*)d_in[1];
  const float* bias = (const float*)d_in[2];
  const int*   rows = (const int*)d_in[3];
  const int*   cols = (const int*)d_in[4];
  float* out = (float*)d_out;

  const int nnz   = in_sizes[1];
  const int n_out = in_sizes[2];
  const int B     = out_size / n_out;           // 32
  const int n_in  = in_sizes[0] / B;            // 65536

  const size_t xTb_bytes = (size_t)n_in * 32 * 2;              // bf16 table
  const size_t xT_bytes  = (size_t)n_in * 32 * sizeof(float);  // fp32 table
  const size_t rp_bytes  = (size_t)(n_out + 1) * sizeof(int);

  if (B == 32 && ws_size >= xTb_bytes + rp_bytes) {
    u32* xTb = (u32*)d_ws;
    int* row_ptr = (int*)((char*)d_ws + xTb_bytes);
    int tblocks = (n_in + 63) / 64;
    int eblocks = (nnz + 255) / 256;
    prep_kernel<<<tblocks + eblocks, 256, 0, stream>>>(
        x, xTb, rows, row_ptr, n_in, n_out, nnz, tblocks);
    ll_main_bf16_kernel<<<(n_out + 63) / 64, 512, 0, stream>>>(
        (const uint4*)xTb, wgt, (const float4*)bias, cols, row_ptr,
        (float4*)out, n_out);
  } else if (B == 32 && ws_size >= xT_bytes + rp_bytes) {
    float* xT = (float*)d_ws;
    int* row_ptr = (int*)((char*)d_ws + xT_bytes);
    transpose_x_kernel<<<(n_in + 63) / 64, 256, 0, stream>>>(x, xT, n_in);
    build_rowptr_bs_kernel<<<(n_out + 256) / 256, 256, 0, stream>>>(rows, row_ptr, nnz, n_out);
    ll_main4_kernel<<<(n_out + 31) / 32, 256, 0, stream>>>(
        (const float4*)xT, wgt, bias, cols, row_ptr, out, n_out);
  } else {
    int total = n_out * B;
    ll_naive_kernel<<<(total + 255) / 256, 256, 0, stream>>>(
        x, wgt, bias, rows, cols, out, n_in, n_out, nnz, B);
  }
}